// Round 3
// baseline (528.771 us; speedup 1.0000x reference)
//
#include <hip/hip_runtime.h>
#include <math.h>

#define NPTS 2000000
#define RR 8
#define GG 32
#define FSTRIDE 520
#define FF 5

__global__ __launch_bounds__(256) void hashgrid_kernel(
    const float* __restrict__ x,
    const float* __restrict__ feat,
    const int* __restrict__ btab,
    float* __restrict__ out)
{
    int n = blockIdx.x * blockDim.x + threadIdx.x;
    if (n >= NPTS) return;

    float x0 = x[3*n+0], x1 = x[3*n+1], x2 = x[3*n+2];
    // Cell assignment via f32 multiply-by-reciprocal: u = fl32(x * 100.0f).
    // (100.0f is exact; this is the hypothesized np-reference semantics.
    //  f32-division-by-0.01f and f64-exact variants both produced sparse
    //  cell flips vs the reference -> catastrophic dfeats errors.)
    float u0 = x0 * 100.0f;
    float u1 = x1 * 100.0f;
    float u2 = x2 * 100.0f;
    float fl0 = floorf(u0), fl1 = floorf(u1), fl2 = floorf(u2);
    int xi0 = (int)fl0, xi1 = (int)fl1, xi2 = (int)fl2;
    float fr0 = u0 - fl0;
    float fr1 = u1 - fl1;
    float fr2 = u2 - fl2;

    // Phase 1: resolve all 8 corners' block indices; gv >= 0 always (x in [0,2.56))
    int offs[8];
    bool ok = true;
    #pragma unroll
    for (int c = 0; c < 8; ++c) {
        int i = (c >> 2) & 1, j = (c >> 1) & 1, k = c & 1;
        int g0 = xi0 + i, g1 = xi1 + j, g2 = xi2 + k;
        int b0 = g0 >> 3, b1 = g1 >> 3, b2 = g2 >> 3;
        bool inb = ((unsigned)b0 < GG) & ((unsigned)b1 < GG) & ((unsigned)b2 < GG);
        int c0 = min(max(b0, 0), GG - 1);
        int c1 = min(max(b1, 0), GG - 1);
        int c2 = min(max(b2, 0), GG - 1);
        int bidx = btab[(c0 * GG + c1) * GG + c2];
        ok &= inb & (bidx >= 0);
        int vidx = ((g0 & 7) * RR + (g1 & 7)) * RR + (g2 & 7);
        offs[c] = max(bidx, 0) * FSTRIDE + vidx;
    }

    float* feats_out = out + (size_t)n * FF;
    float* df_out    = out + (size_t)NPTS * FF + (size_t)n * FF * 3;
    float* m_out     = out + (size_t)NPTS * FF * 4 + n;

    if (!ok) {
        #pragma unroll
        for (int f = 0; f < FF; ++f) feats_out[f] = 0.f;
        #pragma unroll
        for (int q = 0; q < FF * 3; ++q) df_out[q] = 0.f;
        *m_out = 0.f;
        return;
    }

    // Phase 2: gather 8 corners x 5 feats, accumulate trilinear weights + grads
    float accf[FF] = {0.f, 0.f, 0.f, 0.f, 0.f};
    float adx[FF]  = {0.f, 0.f, 0.f, 0.f, 0.f};
    float ady[FF]  = {0.f, 0.f, 0.f, 0.f, 0.f};
    float adz[FF]  = {0.f, 0.f, 0.f, 0.f, 0.f};
    float p0[2] = {1.f - fr0, fr0};
    float p1[2] = {1.f - fr1, fr1};
    float p2[2] = {1.f - fr2, fr2};

    #pragma unroll
    for (int c = 0; c < 8; ++c) {
        int i = (c >> 2) & 1, j = (c >> 1) & 1, k = c & 1;
        float wi = p0[i], wj = p1[j], wk = p2[k];
        float si = i ? 1.f : -1.f;
        float sj = j ? 1.f : -1.f;
        float sk = k ? 1.f : -1.f;
        float w   = wi * wj * wk;
        float dwx = si * wj * wk;
        float dwy = wi * sj * wk;
        float dwz = wi * wj * sk;
        const float* fp = feat + (size_t)offs[c] * FF;
        #pragma unroll
        for (int f = 0; f < FF; ++f) {
            float v = fp[f];
            accf[f] += w   * v;
            adx[f]  += dwx * v;
            ady[f]  += dwy * v;
            adz[f]  += dwz * v;
        }
    }

    const float invV = 100.0f;  // = m/V with m=1
    #pragma unroll
    for (int f = 0; f < FF; ++f) {
        feats_out[f]    = accf[f];
        df_out[f*3 + 0] = adx[f] * invV;
        df_out[f*3 + 1] = ady[f] * invV;
        df_out[f*3 + 2] = adz[f] * invV;
    }
    *m_out = 1.f;
}

extern "C" void kernel_launch(void* const* d_in, const int* in_sizes, int n_in,
                              void* d_out, int out_size, void* d_ws, size_t ws_size,
                              hipStream_t stream) {
    const float* x    = (const float*)d_in[0];
    const float* feat = (const float*)d_in[1];
    const int*   btab = (const int*)d_in[2];
    float* out = (float*)d_out;
    int threads = 256;
    int blocks = (NPTS + threads - 1) / threads;
    hashgrid_kernel<<<blocks, threads, 0, stream>>>(x, feat, btab, out);
}

// Round 4
// 443.020 us; speedup vs baseline: 1.1936x; 1.1936x over previous
//
#include <hip/hip_runtime.h>
#include <math.h>

#define NPTS 2000000
#define GG 32
#define FF 5
#define BLK 256

__global__ __launch_bounds__(256) void hashgrid_kernel(
    const float* __restrict__ x,
    const float* __restrict__ feat,
    const int* __restrict__ btab,
    float* __restrict__ out)
{
    // staging: [0,1280) feats | [1280,5120) dfeats | [5120,5376) mask
    // (region [0,768) first reused to stage x coalesced)
    __shared__ float smem[5376];
    const int tid  = threadIdx.x;
    const int bid  = blockIdx.x;
    const int base = bid * BLK;
    const int cnt  = min(BLK, NPTS - base);   // 256, or 128 for the last block

    // ---- stage x (coalesced float4) ----
    {
        const float4* xin = (const float4*)(x + (size_t)base * 3);
        float4* s4 = (float4*)smem;
        int nf4 = (cnt * 3) >> 2;             // 192 or 96
        for (int i = tid; i < nf4; i += BLK) s4[i] = xin[i];
    }
    __syncthreads();

    float x0 = 0.f, x1 = 0.f, x2 = 0.f;
    if (tid < cnt) { x0 = smem[tid*3+0]; x1 = smem[tid*3+1]; x2 = smem[tid*3+2]; }
    __syncthreads();   // smem reused for outputs below

    float accf[5] = {0,0,0,0,0};
    float adx[5]  = {0,0,0,0,0};
    float ady[5]  = {0,0,0,0,0};
    float adz[5]  = {0,0,0,0,0};
    float mval = 0.f;

    if (tid < cnt) {
        // reference semantics: u = fl32(x * 100.0f), floor/frac in f32
        float u0 = x0 * 100.0f, u1 = x1 * 100.0f, u2 = x2 * 100.0f;
        float fl0 = floorf(u0), fl1 = floorf(u1), fl2 = floorf(u2);
        int xi0 = (int)fl0, xi1 = (int)fl1, xi2 = (int)fl2;
        float fr0 = u0 - fl0, fr1 = u1 - fl1, fr2 = u2 - fl2;

        int offs[8];
        bool ok = true;
        #pragma unroll
        for (int c = 0; c < 8; ++c) {
            int i = (c >> 2) & 1, j = (c >> 1) & 1, k = c & 1;
            int g0 = xi0 + i, g1 = xi1 + j, g2 = xi2 + k;
            int b0 = g0 >> 3, b1 = g1 >> 3, b2 = g2 >> 3;
            bool inb = ((unsigned)b0 < GG) & ((unsigned)b1 < GG) & ((unsigned)b2 < GG);
            int c0 = min(max(b0,0),GG-1), c1 = min(max(b1,0),GG-1), c2 = min(max(b2,0),GG-1);
            int bidx = btab[(c0 * GG + c1) * GG + c2];
            ok &= inb & (bidx >= 0);
            int vidx = ((g0 & 7) * 8 + (g1 & 7)) * 8 + (g2 & 7);
            offs[c] = max(bidx, 0) * 520 + vidx;
        }

        if (ok) {
            mval = 1.f;
            float p0[2] = {1.f - fr0, fr0};
            float p1[2] = {1.f - fr1, fr1};
            float p2[2] = {1.f - fr2, fr2};
            #pragma unroll
            for (int c = 0; c < 8; ++c) {
                int i = (c >> 2) & 1, j = (c >> 1) & 1, k = c & 1;
                float wi = p0[i], wj = p1[j], wk = p2[k];
                float si = i ? 1.f : -1.f;
                float sj = j ? 1.f : -1.f;
                float sk = k ? 1.f : -1.f;
                float w   = wi * wj * wk;
                float dwx = si * wj * wk;
                float dwy = wi * sj * wk;
                float dwz = wi * wj * sk;
                const float* fp = feat + (size_t)offs[c] * 5;
                // vectorized 20B row gather: dwordx4 (align-4, unaligned-mode) + dword
                struct __attribute__((packed, aligned(4))) R16 { float4 v; };
                float4 v4 = ((const R16*)fp)->v;
                float  v5 = fp[4];
                float vv[5] = {v4.x, v4.y, v4.z, v4.w, v5};
                #pragma unroll
                for (int f = 0; f < 5; ++f) {
                    float v = vv[f];
                    accf[f] += w   * v;
                    adx[f]  += dwx * v;
                    ady[f]  += dwy * v;
                    adz[f]  += dwz * v;
                }
            }
        }
    }

    // ---- stage outputs into LDS (odd strides 5/15 -> near-conflict-free) ----
    if (tid < cnt) {
        float* fs = smem + tid * 5;
        #pragma unroll
        for (int f = 0; f < 5; ++f) fs[f] = accf[f];
        float* ds = smem + 1280 + tid * 15;
        #pragma unroll
        for (int f = 0; f < 5; ++f) {
            ds[f*3+0] = adx[f] * 100.0f;
            ds[f*3+1] = ady[f] * 100.0f;
            ds[f*3+2] = adz[f] * 100.0f;
        }
        smem[5120 + tid] = mval;
    }
    __syncthreads();

    // ---- coalesced float4 global writes ----
    {
        const float4* s4 = (const float4*)smem;
        float4* o = (float4*)(out + (size_t)base * 5);
        int nf4 = (cnt * 5) >> 2;             // 320 or 160
        for (int i = tid; i < nf4; i += BLK) o[i] = s4[i];
    }
    {
        const float4* s4 = (const float4*)(smem + 1280);
        float4* o = (float4*)(out + (size_t)NPTS * 5 + (size_t)base * 15);
        int nf4 = (cnt * 15) >> 2;            // 960 or 480
        for (int i = tid; i < nf4; i += BLK) o[i] = s4[i];
    }
    {
        const float4* s4 = (const float4*)(smem + 5120);
        float4* o = (float4*)(out + (size_t)NPTS * 20 + base);
        int nf4 = cnt >> 2;                   // 64 or 32
        for (int i = tid; i < nf4; i += BLK) o[i] = s4[i];
    }
}

extern "C" void kernel_launch(void* const* d_in, const int* in_sizes, int n_in,
                              void* d_out, int out_size, void* d_ws, size_t ws_size,
                              hipStream_t stream) {
    const float* x    = (const float*)d_in[0];
    const float* feat = (const float*)d_in[1];
    const int*   btab = (const int*)d_in[2];
    float* out = (float*)d_out;
    int blocks = (NPTS + BLK - 1) / BLK;      // 7813
    hashgrid_kernel<<<blocks, BLK, 0, stream>>>(x, feat, btab, out);
}